// Round 16
// baseline (123.202 us; speedup 1.0000x reference)
//
#include <hip/hip_runtime.h>
#include <hip/hip_fp16.h>

#define NW 20

typedef _Float16 h2 __attribute__((ext_vector_type(2)));
typedef float    f4 __attribute__((ext_vector_type(4)));

// splat coefficient set for one wire's fused RY*RX unitary
// U = [[a+id, -e-if],[e-if, a-id]]
struct PkW7 { h2 a, d, dn, e, en, f, fn, pad; };   // 32 B

__device__ __forceinline__ h2 pkrtz(float lo, float hi) {
    typedef __fp16 f16x2 __attribute__((ext_vector_type(2)));
    f16x2 v = __builtin_amdgcn_cvt_pkrtz(lo, hi);
    return *reinterpret_cast<h2*>(&v);
}
__device__ __forceinline__ unsigned h2u(h2 v) { return *reinterpret_cast<unsigned*>(&v); }
__device__ __forceinline__ h2 u2h(unsigned v) { return *reinterpret_cast<h2*>(&v); }

// SoA packed butterfly: re/im in separate v2f16, each = 2 batch states.
template<int JB>
__device__ __forceinline__ void stage16s(h2 (&xr)[16], h2 (&xi)[16], const PkW7 u) {
    #pragma unroll
    for (int base = 0; base < 16; ++base)
        if (!(base & (1 << JB))) {
            const int p = base | (1 << JB);
            h2 x0r = xr[base], x0i = xi[base], x1r = xr[p], x1i = xi[p];
            xr[base] = u.a * x0r + u.dn * x0i + u.en * x1r + u.f  * x1i;
            xi[base] = u.a * x0i + u.d  * x0r + u.en * x1i + u.fn * x1r;
            xr[p]    = u.e * x0r + u.f  * x0i + u.a  * x1r + u.d  * x1i;
            xi[p]    = u.e * x0i + u.fn * x0r + u.a  * x1i + u.dn * x1r;
        }
}

// Shuffle butterfly stage on lane-bit JB. Partner via shfl_xor; coefficient
// signs selected by lane side.
template<int JB>
__device__ __forceinline__ void shufstage(h2 (&xr)[16], h2 (&xi)[16], const PkW7 u, int t) {
    const bool hi_ = (t >> JB) & 1;
    const h2 ds_  = hi_ ? u.d  : u.dn;
    const h2 nds_ = hi_ ? u.dn : u.d;
    const h2 es_  = hi_ ? u.e  : u.en;
    #pragma unroll
    for (int r = 0; r < 16; ++r) {
        h2 or_ = xr[r], oi_ = xi[r];
        int pri = __shfl_xor(*reinterpret_cast<int*>(&or_), 1 << JB, 64);
        int pii = __shfl_xor(*reinterpret_cast<int*>(&oi_), 1 << JB, 64);
        h2 pr_ = *reinterpret_cast<h2*>(&pri);
        h2 pi_ = *reinterpret_cast<h2*>(&pii);
        xr[r] = u.a * or_ + ds_  * oi_ + es_ * pr_ + u.f  * pi_;
        xi[r] = u.a * oi_ + nds_ * or_ + es_ * pi_ + u.fn * pr_;
    }
}

// cbuf layout: [0..3] = wire19 f32 (a,d,e,f)*1024 ; then PkW7[20] at cbuf+4
__global__ void setupk(const float* __restrict__ params, float* __restrict__ cbuf) {
    int w = threadIdx.x;
    if (w < NW) {
        double s1, c1, s2, c2;
        sincos(0.5 * (double)params[w],      &s1, &c1);   // RX
        sincos(0.5 * (double)params[w + NW], &s2, &c2);   // RY
        float a = (float)(c1 * c2), d = (float)(s1 * s2);
        float e = (float)(s2 * c1), f = (float)(c2 * s1);
        if (w == 19) {
            cbuf[0] = a * 1024.f; cbuf[1] = d * 1024.f;
            cbuf[2] = e * 1024.f; cbuf[3] = f * 1024.f;
        }
        PkW7 pw;
        pw.a.x  = (_Float16) a; pw.a.y  = (_Float16) a;
        pw.d.x  = (_Float16) d; pw.d.y  = (_Float16) d;
        pw.dn.x = (_Float16)-d; pw.dn.y = (_Float16)-d;
        pw.e.x  = (_Float16) e; pw.e.y  = (_Float16) e;
        pw.en.x = (_Float16)-e; pw.en.y = (_Float16)-e;
        pw.f.x  = (_Float16) f; pw.f.y  = (_Float16) f;
        pw.fn.x = (_Float16)-f; pw.fn.y = (_Float16)-f;
        pw.pad.x = (_Float16)0.f; pw.pad.y = (_Float16)0.f;
        ((PkW7*)(cbuf + 4))[w] = pw;
    }
}

// ---------------------------------------------------------------------------
// Pass 1: wires {19,18} (amp bits 0,1), {17..12} (bits 2..7), {1,0} (bits
// 18,19). Each WAVE independently owns 1024 amps: 256-amp chunk cc (bits
// 8..17 fixed) x quad q = bits 18,19 in reg-pairs. ZERO LDS, ZERO barriers.
// i-layout per wave: amp = 4*ln + (r&3) + q*2^18 + cc*256  (r = (r&3)+4q).
// ---------------------------------------------------------------------------
__global__ __launch_bounds__(256, 4) void pass1(const float* __restrict__ state,
                                                const float* __restrict__ cbuf,
                                                uint2* __restrict__ amp) {
    const int t    = threadIdx.x;
    const int pr   = blockIdx.x >> 8;       // batch pair (pr, pr+16)
    const int cgrp = blockIdx.x & 255;
    const int w = t >> 6, ln = t & 63;
    const int cc = 4 * cgrp + w;            // bits 8..17 value, per wave
    const PkW7* PW = (const PkW7*)(cbuf + 4);
    const float a19 = cbuf[0], d19 = cbuf[1], e19 = cbuf[2], f19 = cbuf[3];

    const float* base0 = state + ((size_t)pr << 20) + ((size_t)cc << 8);
    const float* base1 = base0 + ((size_t)16 << 20);

    h2 xr[16], xi[16];
    // load quad chunks + wire 19 (bit 0, f32, x1024) + pack
    #pragma unroll
    for (int q = 0; q < 4; ++q) {
        f4 v0 = ((const f4*)(base0 + ((size_t)q << 18)))[ln];
        f4 v1 = ((const f4*)(base1 + ((size_t)q << 18)))[ln];
        float r0a = fmaf(a19, v0.x, -e19 * v0.y), i0a = fmaf( d19, v0.x, -f19 * v0.y);
        float r1a = fmaf(e19, v0.x,  a19 * v0.y), i1a = fmaf(-f19, v0.x, -d19 * v0.y);
        float r0b = fmaf(a19, v1.x, -e19 * v1.y), i0b = fmaf( d19, v1.x, -f19 * v1.y);
        float r1b = fmaf(e19, v1.x,  a19 * v1.y), i1b = fmaf(-f19, v1.x, -d19 * v1.y);
        xr[4*q+0] = pkrtz(r0a, r0b); xi[4*q+0] = pkrtz(i0a, i0b);
        xr[4*q+1] = pkrtz(r1a, r1b); xi[4*q+1] = pkrtz(i1a, i1b);
        r0a = fmaf(a19, v0.z, -e19 * v0.w); i0a = fmaf( d19, v0.z, -f19 * v0.w);
        r1a = fmaf(e19, v0.z,  a19 * v0.w); i1a = fmaf(-f19, v0.z, -d19 * v0.w);
        r0b = fmaf(a19, v1.z, -e19 * v1.w); i0b = fmaf( d19, v1.z, -f19 * v1.w);
        r1b = fmaf(e19, v1.z,  a19 * v1.w); i1b = fmaf(-f19, v1.z, -d19 * v1.w);
        xr[4*q+2] = pkrtz(r0a, r0b); xi[4*q+2] = pkrtz(i0a, i0b);
        xr[4*q+3] = pkrtz(r1a, r1b); xi[4*q+3] = pkrtz(i1a, i1b);
    }
    stage16s<1>(xr, xi, PW[18]);            // bit 1  -> wire 18
    // bits 2..7 (lane) -> wires 17..12
    shufstage<0>(xr, xi, PW[17], t);
    shufstage<1>(xr, xi, PW[16], t);
    shufstage<2>(xr, xi, PW[15], t);
    shufstage<3>(xr, xi, PW[14], t);
    shufstage<4>(xr, xi, PW[13], t);
    shufstage<5>(xr, xi, PW[12], t);
    stage16s<2>(xr, xi, PW[1]);             // bit 18 -> wire 1
    stage16s<3>(xr, xi, PW[0]);             // bit 19 -> wire 0

    // store: same layout; per q two uint4 (16B/lane)
    uint2* dstb = amp + ((size_t)pr << 20) + ((size_t)cc << 8);
    #pragma unroll
    for (int q = 0; q < 4; ++q) {
        uint4* d4 = (uint4*)(dstb + ((size_t)q << 18));
        uint4 wa, wb;
        wa.x = h2u(xr[4*q+0]); wa.y = h2u(xi[4*q+0]);
        wa.z = h2u(xr[4*q+1]); wa.w = h2u(xi[4*q+1]);
        wb.x = h2u(xr[4*q+2]); wb.y = h2u(xi[4*q+2]);
        wb.z = h2u(xr[4*q+3]); wb.w = h2u(xi[4*q+3]);
        d4[2*ln]     = wa;
        d4[2*ln + 1] = wb;
    }
}

// ---------------------------------------------------------------------------
// Pass 2: wires 11..2 (amp bits 8..17 = m) + fused |psi|^2 * g(y).
// Block: fixed (q = bits 18,19, l8-group of 4). m decomposition (old):
//   mb03 = lane bits 2..5, mb47 = regs, mb89 = wave. After ONE exchange:
//   regs' = mb67|mb89, wave' = mb45. g = Atab[m] + sigma(m)*Bl (verified
//   re-factorization for this split; q-signs folded per block).
// ---------------------------------------------------------------------------
__global__ __launch_bounds__(256, 4) void pass2(const uint2* __restrict__ amp,
                                                const float* __restrict__ cbuf,
                                                const float* __restrict__ Wv,
                                                float* __restrict__ pws) {
    __shared__ h2    L[4224];
    __shared__ float Atab[1024];
    __shared__ float wred[8];
    const int t    = threadIdx.x;
    const int pr   = blockIdx.x >> 8;
    const int rest = blockIdx.x & 255;
    const int cbl  = rest >> 2, q = rest & 3;
    const PkW7* PW = (const PkW7*)(cbuf + 4);
    const float sq  = (__popc(q) & 1) ? -1.f : 1.f;    // (-1)^{b18+b19}
    const float sq1 = (q >> 1) ? -1.f : 1.f;           // (-1)^{b19}

    // Atab[m] = W0*sq1 + sq*(W1 + sum_{i=2..10} W_i*(-1)^{par(m>>(11-i))})
    #pragma unroll
    for (int mm = t; mm < 1024; mm += 256) {
        float A = Wv[1];
        #pragma unroll
        for (int i = 2; i <= 10; ++i)
            A += Wv[i] * (1.f - 2.f * (float)(__popc(mm >> (11 - i)) & 1));
        Atab[mm] = fmaf(sq, A, Wv[0] * sq1);
    }
    // Bl: l8 = 4*cbl + (t&3): sq*(W11 + sum_{i=12..19} Wi*(-1)^{par(l8>>(19-i))})
    const int l8 = 4 * cbl + (t & 3);
    float Bl = Wv[11];
    #pragma unroll
    for (int i = 12; i <= 19; ++i)
        Bl += Wv[i] * (1.f - 2.f * (float)(__popc(l8 >> (19 - i)) & 1));
    Bl *= sq;

    // load: m = mb03 + 16*(r&3) + 64*(r>>2) + 256*w
    const int mb03 = (t >> 2) & 15, w = t >> 6;
    const uint2* src = amp + ((size_t)pr << 20) + ((size_t)q << 18) + 4 * cbl + (t & 3);
    h2 xr[16], xi[16];
    #pragma unroll
    for (int r = 0; r < 16; ++r) {
        const int m = mb03 + 16 * (r & 3) + 64 * (r >> 2) + 256 * w;
        uint2 v = src[(size_t)m << 8];
        xr[r] = u2h(v.x); xi[r] = u2h(v.y);
    }
    // mb0..3 (lane bits 2..5) -> wires 11,10,9,8
    shufstage<2>(xr, xi, PW[11], t);
    shufstage<3>(xr, xi, PW[10], t);
    shufstage<4>(xr, xi, PW[9],  t);
    shufstage<5>(xr, xi, PW[8],  t);
    // mb4..7 (regs) -> wires 7,6,5,4
    stage16s<0>(xr, xi, PW[7]);
    stage16s<1>(xr, xi, PW[6]);
    stage16s<2>(xr, xi, PW[5]);
    stage16s<3>(xr, xi, PW[4]);

    // ONE exchange (component-sequential): regs mb47|wave mb89 -> regs mb67|mb89
    // write SK(s_old): (t&63)+((t&63)>>5) + 66*r + 1056*w
    // read  SK(s_new): (t&63)+((t&63)>>5) + 66*w + 264*r'
    const int pb = (t & 63) + ((t & 63) >> 5);
    #pragma unroll
    for (int r = 0; r < 16; ++r) L[pb + 66 * r + 1056 * w] = xr[r];
    __syncthreads();                        // also publishes Atab
    #pragma unroll
    for (int r = 0; r < 16; ++r) xr[r] = L[pb + 66 * w + 264 * r];
    __syncthreads();
    #pragma unroll
    for (int r = 0; r < 16; ++r) L[pb + 66 * r + 1056 * w] = xi[r];
    __syncthreads();
    #pragma unroll
    for (int r = 0; r < 16; ++r) xi[r] = L[pb + 66 * w + 264 * r];

    // mb8,9 (regs' high bits) -> wires 3,2
    stage16s<2>(xr, xi, PW[3]);
    stage16s<3>(xr, xi, PW[2]);

    // epilogue: m = mb03 + 16*(t>>6) + 64*(r'&3) + 256*(r'>>2)
    const int mbase = mb03 + 16 * w;
    const float s_tw = (__popc(mbase) & 1) ? -1.f : 1.f;
    float acc0 = 0.f, acc1 = 0.f;
    #pragma unroll
    for (int r = 0; r < 16; ++r) {
        const int m = mbase + 64 * (r & 3) + 256 * (r >> 2);
        const float sg = (__popc(r) & 1) ? -s_tw : s_tw;   // sigma(m)
        const float g  = fmaf(sg, Bl, Atab[m]);
        float vrx = (float)xr[r].x, vry = (float)xr[r].y;
        float vix = (float)xi[r].x, viy = (float)xi[r].y;
        acc0 = fmaf(fmaf(vrx, vrx, vix * vix), g, acc0);
        acc1 = fmaf(fmaf(vry, vry, viy * viy), g, acc1);
    }
    #pragma unroll
    for (int off = 32; off > 0; off >>= 1) {
        acc0 += __shfl_down(acc0, off, 64);
        acc1 += __shfl_down(acc1, off, 64);
    }
    if ((t & 63) == 0) { wred[w * 2] = acc0; wred[w * 2 + 1] = acc1; }
    __syncthreads();
    if (t < 2)
        pws[blockIdx.x * 2 + t] = (wred[t] + wred[2 + t]) + (wred[4 + t] + wred[6 + t]);
}

// ---------------------------------------------------------------------------
// Final: deterministic reduction of 256 partials per batch, undo 2^20 scale.
// ---------------------------------------------------------------------------
__global__ void finalk(const float* __restrict__ pws, const float* __restrict__ bias,
                       float* __restrict__ out) {
    const int t = threadIdx.x;
    const int b = t >> 3, j = t & 7;
    const int pr = b & 15, sl = b >> 4;
    float s = 0.f;
    #pragma unroll 4
    for (int k = 0; k < 32; ++k) {
        const int c = j * 32 + k;
        s += pws[(pr * 256 + c) * 2 + sl];
    }
    s += __shfl_down(s, 4, 8);
    s += __shfl_down(s, 2, 8);
    s += __shfl_down(s, 1, 8);
    if (j == 0) out[b] = s * (1.f / 1048576.f) + bias[0];
}

extern "C" void kernel_launch(void* const* d_in, const int* in_sizes, int n_in,
                              void* d_out, int out_size, void* d_ws, size_t ws_size,
                              hipStream_t stream) {
    const float* state  = (const float*)d_in[0];   // (32, 2^20) f32
    const float* params = (const float*)d_in[1];   // (40,) f32
    const float* Wv     = (const float*)d_in[2];   // (1,20) f32
    const float* bias   = (const float*)d_in[3];   // (1,)  f32
    float* out = (float*)d_out;                    // (32,) f32

    const size_t AMPB = (size_t)16 * (1u << 20) * 8;   // 128 MiB intermediate
    uint2* amp  = (uint2*)d_ws;
    float* pws  = (float*)((char*)d_ws + AMPB);
    float* cbuf = (float*)((char*)d_ws + AMPB + 65536);

    setupk<<<1, 64, 0, stream>>>(params, cbuf);
    pass1 <<<16 * 256, 256, 0, stream>>>(state, cbuf, amp);
    pass2 <<<16 * 256, 256, 0, stream>>>(amp, cbuf, Wv, pws);
    finalk<<<1, 256, 0, stream>>>(pws, bias, out);
}